// Round 2
// baseline (106.086 us; speedup 1.0000x reference)
//
#include <hip/hip_runtime.h>
#include <hip/hip_bf16.h>

// Problem constants
#define BATCH 4096
#define FIELD 20000
#define EMBED 64
#define KSTEPS 625          // FIELD / 32 k per MFMA step
#define KC     25           // number of K-chunks (reduced by reduce_kernel)
#define SPW    25           // K-steps per wave = KSTEPS / KC
#define MTILES 256          // BATCH / 16 rows per wave
#define TOTAL_WAVES (MTILES * KC)      // 6400
#define WSWZ_DWORDS (FIELD * EMBED / 2)        // 640000 dwords = 2.56 MB
#define PART_STRIDE (MTILES * 1024)            // f32 per kc slice (256 tiles * 16*64)

typedef __attribute__((ext_vector_type(4))) float  f32x4;
typedef __attribute__((ext_vector_type(8))) short  short8;   // 8 bf16 MFMA frag
typedef __attribute__((ext_vector_type(4))) int    i32x4;
typedef __attribute__((ext_vector_type(4))) unsigned int u32x4;

__device__ __forceinline__ unsigned bf16_rtne(float f) {
    unsigned u = __builtin_bit_cast(unsigned, f);
    return (u + 0x7FFFu + ((u >> 16) & 1u)) >> 16;   // round-to-nearest-even
}

// Pre-swizzle W (f32 [FIELD][EMBED]) -> bf16 MFMA-B-fragment order, via LDS:
// coalesced float4 loads, padded-LDS transpose, coalesced dwordx4 stores.
// dword o2 = ((s*4 + t)*64 + lane)*4 + j2 holds B[k][col] | B[k+1][col]<<16,
// k = 32*s + (lane>>4)*8 + 2*j2, col = 16*t + (lane&15).
__global__ __launch_bounds__(256) void prep_w_kernel(const float* __restrict__ W,
                                                     unsigned int* __restrict__ Wswz) {
    __shared__ float lds[32 * 65];               // [32 k][64 col] padded +1
    const int t  = threadIdx.x;
    const int s0 = blockIdx.x;                   // s-chunk: 32 k rows

    const float4* src = (const float4*)(W + (size_t)s0 * 2048);
    float4 a = src[t * 2 + 0];
    float4 b = src[t * 2 + 1];
    int l  = t * 8;                              // linear elem in [32][64] chunk
    int kl = l >> 6, c = l & 63;                 // 8 elems stay within one k row
    float* dst = lds + kl * 65 + c;
    dst[0] = a.x; dst[1] = a.y; dst[2] = a.z; dst[3] = a.w;
    dst[4] = b.x; dst[5] = b.y; dst[6] = b.z; dst[7] = b.w;
    __syncthreads();

    const int lane = t & 63, tq = t >> 6;        // 4 col-frags x 64 lanes
    const int khi = lane >> 4, lrow = lane & 15;
    const int col = tq * 16 + lrow;
    u32x4 o;
#pragma unroll
    for (int j2 = 0; j2 < 4; ++j2) {
        int kloc = khi * 8 + 2 * j2;
        float w0 = lds[kloc * 65 + col];
        float w1 = lds[(kloc + 1) * 65 + col];
        o[j2] = bf16_rtne(w0) | (bf16_rtne(w1) << 16);
    }
    *(u32x4*)(Wswz + ((size_t)(s0 * 4 + tq) * 64 + lane) * 4) = o;
}

// Main: stream 328 MB of indices, mask -> bf16 {0,1} A-frags, MFMA vs
// pre-swizzled B, store per-(kc,mtile) partial tiles to ws (fragment order,
// fully coalesced dwordx4). No atomics.
__global__ __launch_bounds__(256) void emb_mfma_kernel(const int* __restrict__ idxm,
                                                       const unsigned int* __restrict__ Wswz,
                                                       float* __restrict__ P) {
    const int lane  = threadIdx.x & 63;
    const int w     = blockIdx.x * 4 + (threadIdx.x >> 6);
    const int mtile = w % MTILES;
    const int kc    = w / MTILES;
    const int lrow  = lane & 15;
    const int khi   = lane >> 4;                 // 0..3
    const int row   = mtile * 16 + lrow;

    const i32x4* pA = (const i32x4*)(idxm + (size_t)row * FIELD
                                     + (size_t)kc * SPW * 32 + khi * 8);
    const short8* pB = (const short8*)Wswz + (size_t)kc * SPW * 4 * 64 + lane;

    f32x4 acc0 = {0.f, 0.f, 0.f, 0.f};
    f32x4 acc1 = acc0, acc2 = acc0, acc3 = acc0;

#pragma unroll 5
    for (int s = 0; s < SPW; ++s) {
        i32x4 x = pA[0];
        i32x4 y = pA[1];
        pA += 8;                                 // advance 32 ints

        unsigned m0 = (x.x != 0 ? 0x3F80u : 0u) | (x.y != 0 ? 0x3F800000u : 0u);
        unsigned m1 = (x.z != 0 ? 0x3F80u : 0u) | (x.w != 0 ? 0x3F800000u : 0u);
        unsigned m2 = (y.x != 0 ? 0x3F80u : 0u) | (y.y != 0 ? 0x3F800000u : 0u);
        unsigned m3 = (y.z != 0 ? 0x3F80u : 0u) | (y.w != 0 ? 0x3F800000u : 0u);
        u32x4 av = {m0, m1, m2, m3};
        short8 afrag = __builtin_bit_cast(short8, av);

        short8 b0 = pB[0];
        short8 b1 = pB[64];
        short8 b2 = pB[128];
        short8 b3 = pB[192];
        pB += 256;

        acc0 = __builtin_amdgcn_mfma_f32_16x16x32_bf16(afrag, b0, acc0, 0, 0, 0);
        acc1 = __builtin_amdgcn_mfma_f32_16x16x32_bf16(afrag, b1, acc1, 0, 0, 0);
        acc2 = __builtin_amdgcn_mfma_f32_16x16x32_bf16(afrag, b2, acc2, 0, 0, 0);
        acc3 = __builtin_amdgcn_mfma_f32_16x16x32_bf16(afrag, b3, acc3, 0, 0, 0);
    }

    // Partial-tile store, fragment order: [(kc,mtile)][frag][lane][4]
    float* pP = P + (size_t)(kc * MTILES + mtile) * 1024 + lane * 4;
    *(f32x4*)(pP + 0)   = acc0;
    *(f32x4*)(pP + 256) = acc1;
    *(f32x4*)(pP + 512) = acc2;
    *(f32x4*)(pP + 768) = acc3;
}

// Sum KC partials per output element and write d_out (every element written
// every call -> no zeroing kernel needed).
__global__ __launch_bounds__(256) void reduce_kernel(const float* __restrict__ P,
                                                     float* __restrict__ out) {
    const int tid = blockIdx.x * 256 + threadIdx.x;   // 0 .. 256K-1
    float s = 0.f;
#pragma unroll
    for (int kc = 0; kc < KC; ++kc)
        s += P[(size_t)kc * PART_STRIDE + tid];

    // tid = ((mtile*4 + f)*64 + lane)*4 + i  ->  D layout: col=lane&15, row=khi*4+i
    const int i     = tid & 3;
    const int lane  = (tid >> 2) & 63;
    const int f     = (tid >> 8) & 3;
    const int mtile = tid >> 10;
    const int row   = mtile * 16 + (lane >> 4) * 4 + i;
    const int col   = f * 16 + (lane & 15);
    out[(size_t)row * EMBED + col] = s;
}

extern "C" void kernel_launch(void* const* d_in, const int* in_sizes, int n_in,
                              void* d_out, int out_size, void* d_ws, size_t ws_size,
                              hipStream_t stream) {
    const int*   idxm = (const int*)d_in[0];     // [4096][20000] int32
    const float* W    = (const float*)d_in[1];   // [20000][64] f32
    float*       out  = (float*)d_out;           // [4096][64] f32

    unsigned int* Wswz = (unsigned int*)d_ws;              // 2.56 MB
    float*        P    = (float*)((char*)d_ws + (size_t)WSWZ_DWORDS * 4);  // 26.2 MB partials

    hipLaunchKernelGGL(prep_w_kernel, dim3(KSTEPS), dim3(256), 0, stream, W, Wswz);
    hipLaunchKernelGGL(emb_mfma_kernel, dim3(TOTAL_WAVES / 4), dim3(256), 0, stream,
                       idxm, Wswz, P);
    hipLaunchKernelGGL(reduce_kernel, dim3(BATCH * EMBED / 256), dim3(256), 0, stream,
                       P, out);
}

// Round 3
// 104.640 us; speedup vs baseline: 1.0138x; 1.0138x over previous
//
#include <hip/hip_runtime.h>
#include <hip/hip_bf16.h>

// Problem constants
#define BATCH 4096
#define FIELD 20000
#define EMBED 64
#define KSTEPS 625          // FIELD / 32 k per MFMA step
#define KC     25           // number of K-chunks (reduced by reduce_kernel)
#define SPW    25           // K-steps per wave = KSTEPS / KC
#define MTILES 256          // BATCH / 16 rows per wave
#define TOTAL_WAVES (MTILES * KC)      // 6400
#define WSWZ_DWORDS (FIELD * EMBED / 2)        // 640000 dwords = 2.56 MB
#define PART_STRIDE (MTILES * 1024)            // f32 per kc slice

typedef __attribute__((ext_vector_type(4))) float  f32x4;
typedef __attribute__((ext_vector_type(8))) short  short8;   // 8 bf16 MFMA frag
typedef __attribute__((ext_vector_type(4))) int    i32x4;
typedef __attribute__((ext_vector_type(4))) unsigned int u32x4;

__device__ __forceinline__ unsigned bf16_rtne(float f) {
    unsigned u = __builtin_bit_cast(unsigned, f);
    return (u + 0x7FFFu + ((u >> 16) & 1u)) >> 16;   // round-to-nearest-even
}

// Pre-swizzle W (f32 [FIELD][EMBED]) -> bf16 MFMA-B-fragment order, via LDS.
__global__ __launch_bounds__(256) void prep_w_kernel(const float* __restrict__ W,
                                                     unsigned int* __restrict__ Wswz) {
    __shared__ float lds[32 * 65];               // [32 k][64 col] padded +1
    const int t  = threadIdx.x;
    const int s0 = blockIdx.x;                   // s-chunk: 32 k rows

    const float4* src = (const float4*)(W + (size_t)s0 * 2048);
    float4 a = src[t * 2 + 0];
    float4 b = src[t * 2 + 1];
    int l  = t * 8;
    int kl = l >> 6, c = l & 63;
    float* dst = lds + kl * 65 + c;
    dst[0] = a.x; dst[1] = a.y; dst[2] = a.z; dst[3] = a.w;
    dst[4] = b.x; dst[5] = b.y; dst[6] = b.z; dst[7] = b.w;
    __syncthreads();

    const int lane = t & 63, tq = t >> 6;
    const int khi = lane >> 4, lrow = lane & 15;
    const int col = tq * 16 + lrow;
    u32x4 o;
#pragma unroll
    for (int j2 = 0; j2 < 4; ++j2) {
        int kloc = khi * 8 + 2 * j2;
        float w0 = lds[kloc * 65 + col];
        float w1 = lds[(kloc + 1) * 65 + col];
        o[j2] = bf16_rtne(w0) | (bf16_rtne(w1) << 16);
    }
    *(u32x4*)(Wswz + ((size_t)(s0 * 4 + tq) * 64 + lane) * 4) = o;
}

__device__ __forceinline__ short8 mask_to_afrag(i32x4 x, i32x4 y) {
    unsigned m0 = (x.x != 0 ? 0x3F80u : 0u) | (x.y != 0 ? 0x3F800000u : 0u);
    unsigned m1 = (x.z != 0 ? 0x3F80u : 0u) | (x.w != 0 ? 0x3F800000u : 0u);
    unsigned m2 = (y.x != 0 ? 0x3F80u : 0u) | (y.y != 0 ? 0x3F800000u : 0u);
    unsigned m3 = (y.z != 0 ? 0x3F80u : 0u) | (y.w != 0 ? 0x3F800000u : 0u);
    u32x4 av = {m0, m1, m2, m3};
    return __builtin_bit_cast(short8, av);
}

// Main: stream 328 MB of indices via MFMA. 1-deep register prefetch of both
// A (indices) and B (swizzled W) keeps ~2 KB/wave of HBM loads in flight;
// __launch_bounds__(256,4) caps VGPR at 128 -> 16 waves/CU -> ~32 KB/CU
// in flight > the ~22 KB needed to sustain ~6.7 TB/s.
__global__ __launch_bounds__(256, 4) void emb_mfma_kernel(const int* __restrict__ idxm,
                                                          const unsigned int* __restrict__ Wswz,
                                                          float* __restrict__ P) {
    const int lane  = threadIdx.x & 63;
    const int w     = blockIdx.x * 4 + (threadIdx.x >> 6);
    const int mtile = w % MTILES;
    const int kc    = w / MTILES;
    const int lrow  = lane & 15;
    const int khi   = lane >> 4;                 // 0..3
    const int row   = mtile * 16 + lrow;

    const i32x4* pA = (const i32x4*)(idxm + (size_t)row * FIELD
                                     + (size_t)kc * SPW * 32 + khi * 8);
    const short8* pB = (const short8*)Wswz + (size_t)kc * SPW * 4 * 64 + lane;

    // prologue: step-0 loads
    i32x4 x0 = pA[0];
    i32x4 y0 = pA[1];
    short8 b0 = pB[0], b1 = pB[64], b2 = pB[128], b3 = pB[192];

    f32x4 acc0 = {0.f, 0.f, 0.f, 0.f};
    f32x4 acc1 = acc0, acc2 = acc0, acc3 = acc0;

#pragma unroll 2
    for (int s = 0; s < SPW - 1; ++s) {
        pA += 8; pB += 256;
        // prefetch step s+1 (stays in-bounds: s+1 <= SPW-1)
        i32x4 x1 = pA[0];
        i32x4 y1 = pA[1];
        short8 nb0 = pB[0], nb1 = pB[64], nb2 = pB[128], nb3 = pB[192];

        short8 afrag = mask_to_afrag(x0, y0);
        acc0 = __builtin_amdgcn_mfma_f32_16x16x32_bf16(afrag, b0, acc0, 0, 0, 0);
        acc1 = __builtin_amdgcn_mfma_f32_16x16x32_bf16(afrag, b1, acc1, 0, 0, 0);
        acc2 = __builtin_amdgcn_mfma_f32_16x16x32_bf16(afrag, b2, acc2, 0, 0, 0);
        acc3 = __builtin_amdgcn_mfma_f32_16x16x32_bf16(afrag, b3, acc3, 0, 0, 0);

        x0 = x1; y0 = y1;
        b0 = nb0; b1 = nb1; b2 = nb2; b3 = nb3;
    }
    // peeled last step (no prefetch -> no OOB read)
    {
        short8 afrag = mask_to_afrag(x0, y0);
        acc0 = __builtin_amdgcn_mfma_f32_16x16x32_bf16(afrag, b0, acc0, 0, 0, 0);
        acc1 = __builtin_amdgcn_mfma_f32_16x16x32_bf16(afrag, b1, acc1, 0, 0, 0);
        acc2 = __builtin_amdgcn_mfma_f32_16x16x32_bf16(afrag, b2, acc2, 0, 0, 0);
        acc3 = __builtin_amdgcn_mfma_f32_16x16x32_bf16(afrag, b3, acc3, 0, 0, 0);
    }

    // Partial-tile store, fragment order: [(kc,mtile)][frag][lane][4]
    float* pP = P + (size_t)(kc * MTILES + mtile) * 1024 + lane * 4;
    *(f32x4*)(pP + 0)   = acc0;
    *(f32x4*)(pP + 256) = acc1;
    *(f32x4*)(pP + 512) = acc2;
    *(f32x4*)(pP + 768) = acc3;
}

// Sum KC partials per output element and write d_out.
__global__ __launch_bounds__(256) void reduce_kernel(const float* __restrict__ P,
                                                     float* __restrict__ out) {
    const int tid = blockIdx.x * 256 + threadIdx.x;   // 0 .. 256K-1
    float s = 0.f;
#pragma unroll
    for (int kc = 0; kc < KC; ++kc)
        s += P[(size_t)kc * PART_STRIDE + tid];

    // tid = ((mtile*4 + f)*64 + lane)*4 + i  ->  D: col=lane&15, row=khi*4+i
    const int i     = tid & 3;
    const int lane  = (tid >> 2) & 63;
    const int f     = (tid >> 8) & 3;
    const int mtile = tid >> 10;
    const int row   = mtile * 16 + (lane >> 4) * 4 + i;
    const int col   = f * 16 + (lane & 15);
    out[(size_t)row * EMBED + col] = s;
}

extern "C" void kernel_launch(void* const* d_in, const int* in_sizes, int n_in,
                              void* d_out, int out_size, void* d_ws, size_t ws_size,
                              hipStream_t stream) {
    const int*   idxm = (const int*)d_in[0];     // [4096][20000] int32
    const float* W    = (const float*)d_in[1];   // [20000][64] f32
    float*       out  = (float*)d_out;           // [4096][64] f32

    unsigned int* Wswz = (unsigned int*)d_ws;              // 2.56 MB
    float*        P    = (float*)((char*)d_ws + (size_t)WSWZ_DWORDS * 4);  // 26.2 MB

    hipLaunchKernelGGL(prep_w_kernel, dim3(KSTEPS), dim3(256), 0, stream, W, Wswz);
    hipLaunchKernelGGL(emb_mfma_kernel, dim3(TOTAL_WAVES / 4), dim3(256), 0, stream,
                       idxm, Wswz, P);
    hipLaunchKernelGGL(reduce_kernel, dim3(BATCH * EMBED / 256), dim3(256), 0, stream,
                       P, out);
}

// Round 4
// 90.109 us; speedup vs baseline: 1.1773x; 1.1613x over previous
//
#include <hip/hip_runtime.h>
#include <hip/hip_bf16.h>

// Problem constants
#define BATCH 4096
#define FIELD 20000
#define EMBED 64
#define KC     25           // K-chunks per row
#define KSPAN  800          // ints per row per kc chunk (FIELD/KC)
#define SPW    25           // MFMA k-steps per wave (KSPAN/32)
#define MTILES 256          // BATCH/16
#define LROW_STRIDE 26      // LDS words per row (25 + pad for u64 align & banks)
#define WAVE_LDS (16 * LROW_STRIDE)   // 416 words per wave

typedef __attribute__((ext_vector_type(4))) float  f32x4;
typedef __attribute__((ext_vector_type(8))) short  short8;   // 8 bf16 MFMA frag
typedef __attribute__((ext_vector_type(4))) unsigned int u32x4;
typedef unsigned long long u64;

__device__ __forceinline__ unsigned bf16_rtne(float f) {
    unsigned u = __builtin_bit_cast(unsigned, f);
    return (u + 0x7FFFu + ((u >> 16) & 1u)) >> 16;   // round-to-nearest-even
}

// Pre-swizzle W -> bf16 MFMA-B-fragment order (as R2, verified) AND zero d_out
// (atomics accumulate, harness doesn't re-zero between replays).
__global__ __launch_bounds__(256) void prep_w_kernel(const float* __restrict__ W,
                                                     unsigned int* __restrict__ Wswz,
                                                     float* __restrict__ out) {
    if (blockIdx.x < 512) {            // zero 1 MB output: 512 blocks x 256 x float2
        float2 z; z.x = 0.f; z.y = 0.f;
        ((float2*)out)[blockIdx.x * 256 + threadIdx.x] = z;
    }

    __shared__ float lds[32 * 65];               // [32 k][64 col] padded +1
    const int t  = threadIdx.x;
    const int s0 = blockIdx.x;                   // s-chunk: 32 k rows

    const float4* src = (const float4*)(W + (size_t)s0 * 2048);
    float4 a = src[t * 2 + 0];
    float4 b = src[t * 2 + 1];
    int l  = t * 8;
    int kl = l >> 6, c = l & 63;
    float* dst = lds + kl * 65 + c;
    dst[0] = a.x; dst[1] = a.y; dst[2] = a.z; dst[3] = a.w;
    dst[4] = b.x; dst[5] = b.y; dst[6] = b.z; dst[7] = b.w;
    __syncthreads();

    const int lane = t & 63, tq = t >> 6;
    const int khi = lane >> 4, lrow = lane & 15;
    const int col = tq * 16 + lrow;
    u32x4 o;
#pragma unroll
    for (int j2 = 0; j2 < 4; ++j2) {
        int kloc = khi * 8 + 2 * j2;
        float w0 = lds[kloc * 65 + col];
        float w1 = lds[(kloc + 1) * 65 + col];
        o[j2] = bf16_rtne(w0) | (bf16_rtne(w1) << 16);
    }
    *(u32x4*)(Wswz + ((size_t)(s0 * 4 + tq) * 64 + lane) * 4) = o;
}

// Main kernel. Per wave (mtile, kc):
//  Phase 1 (compress): 16 rows x 800 ints read SEQUENTIALLY (256 B/instr,
//    3.2 KB runs per row) -> __ballot -> 16x25 mask words in wave-private LDS.
//    This replaces the 16-way x 128 B strided gather that ran at ~50% DRAM eff.
//  Phase 2 (expand+MFMA): per k-step, ds_read one mask word per row
//    (conflict-free: stride 26, 16 distinct banks, 4-way bcast), expand byte
//    khi*8..+7 to packed-bf16 A-frag, MFMA vs L2-resident B-frags.
//  Epilogue: atomicAdd 16x64 tile (output L2-resident; R1 measured this free).
__global__ __launch_bounds__(256) void emb_mfma_kernel(const int* __restrict__ idxm,
                                                       const unsigned int* __restrict__ Wswz,
                                                       float* __restrict__ out) {
    __shared__ unsigned lmask[4 * WAVE_LDS];
    const int lane  = threadIdx.x & 63;
    const int widx  = threadIdx.x >> 6;
    const int w     = blockIdx.x * 4 + widx;
    const int mtile = w % MTILES;
    const int kc    = w / MTILES;
    const int lrow  = lane & 15;
    const int khi   = lane >> 4;                 // 0..3
    unsigned* lm = lmask + widx * WAVE_LDS;

    // ---- Phase 1: compress ----
    for (int r = 0; r < 16; ++r) {
        const int* rp = idxm + (size_t)(mtile * 16 + r) * FIELD + kc * KSPAN;
        int v[13];
#pragma unroll
        for (int c = 0; c < 12; ++c) v[c] = rp[c * 64 + lane];
        v[12] = 1;
        if (lane < 32) v[12] = rp[768 + lane];
#pragma unroll
        for (int c = 0; c < 12; ++c) {
            u64 b = __ballot(v[c] != 0);          // bit l = (int 64c+l) != 0
            if (lane == 0)
                *(u64*)&lm[r * LROW_STRIDE + 2 * c] = b;   // words 2c,2c+1 (8B-aligned)
        }
        u64 bt = __ballot(v[12] != 0);            // low 32 bits = k 768..799
        if (lane == 0)
            lm[r * LROW_STRIDE + 24] = (unsigned)bt;
    }
    __syncthreads();

    // ---- Phase 2: expand + MFMA ----
    const short8* pB = (const short8*)Wswz + (size_t)kc * SPW * 4 * 64 + lane;
    const unsigned* mrow = lm + lrow * LROW_STRIDE;

    f32x4 acc0 = {0.f, 0.f, 0.f, 0.f};
    f32x4 acc1 = acc0, acc2 = acc0, acc3 = acc0;

#pragma unroll 5
    for (int s = 0; s < SPW; ++s) {
        unsigned Mw = mrow[s];                    // 32 k-bits for this row, step s
        short8 b0 = pB[0], b1 = pB[64], b2 = pB[128], b3 = pB[192];
        pB += 256;

        unsigned mb = Mw >> (khi * 8);            // this lane's 8 k-bits
        u32x4 av;
#pragma unroll
        for (int j = 0; j < 4; ++j)
            av[j] = (((mb >> (2 * j)) & 1u) ? 0x3F80u : 0u)
                  | (((mb >> (2 * j + 1)) & 1u) ? 0x3F800000u : 0u);
        short8 afrag = __builtin_bit_cast(short8, av);

        acc0 = __builtin_amdgcn_mfma_f32_16x16x32_bf16(afrag, b0, acc0, 0, 0, 0);
        acc1 = __builtin_amdgcn_mfma_f32_16x16x32_bf16(afrag, b1, acc1, 0, 0, 0);
        acc2 = __builtin_amdgcn_mfma_f32_16x16x32_bf16(afrag, b2, acc2, 0, 0, 0);
        acc3 = __builtin_amdgcn_mfma_f32_16x16x32_bf16(afrag, b3, acc3, 0, 0, 0);
    }

    // ---- Epilogue: atomic accumulate (D: col=lane&15, row=khi*4+i) ----
    float* obase = out + (size_t)mtile * 16 * EMBED;
#pragma unroll
    for (int i = 0; i < 4; ++i) {
        int orow = khi * 4 + i;
        atomicAdd(obase + (size_t)orow * EMBED +      lrow, acc0[i]);
        atomicAdd(obase + (size_t)orow * EMBED + 16 + lrow, acc1[i]);
        atomicAdd(obase + (size_t)orow * EMBED + 32 + lrow, acc2[i]);
        atomicAdd(obase + (size_t)orow * EMBED + 48 + lrow, acc3[i]);
    }
}

extern "C" void kernel_launch(void* const* d_in, const int* in_sizes, int n_in,
                              void* d_out, int out_size, void* d_ws, size_t ws_size,
                              hipStream_t stream) {
    const int*   idxm = (const int*)d_in[0];     // [4096][20000] int32
    const float* W    = (const float*)d_in[1];   // [20000][64] f32
    float*       out  = (float*)d_out;           // [4096][64] f32
    unsigned int* Wswz = (unsigned int*)d_ws;    // 2.56 MB swizzled bf16 W

    hipLaunchKernelGGL(prep_w_kernel, dim3(FIELD / 32), dim3(256), 0, stream,
                       W, Wswz, out);
    hipLaunchKernelGGL(emb_mfma_kernel, dim3(MTILES * KC / 4), dim3(256), 0, stream,
                       idxm, Wswz, out);
}